// Round 1
// baseline (354.658 us; speedup 1.0000x reference)
//
#include <hip/hip_runtime.h>
#include <hip/hip_bf16.h>
#include <stdint.h>

#define M_DIM 8192
#define N_DIM 4096
#define K_DIM 4096

typedef __attribute__((ext_vector_type(8))) short short8;
typedef __attribute__((ext_vector_type(4))) float floatx4;
typedef __attribute__((ext_vector_type(8))) unsigned short ushort8;

typedef unsigned short ushort_t;

__device__ inline ushort_t f2bf(float f) {
    __hip_bfloat16 h = __float2bfloat16(f);  // RNE
    return *reinterpret_cast<ushort_t*>(&h);
}

// ---------------- pre-pass 1: x f32 -> bf16 (vectorized, memory-bound) ---------------
__global__ void cvt_x_kernel(const float* __restrict__ in, ushort_t* __restrict__ out, int n4) {
    int i = blockIdx.x * blockDim.x + threadIdx.x;
    int stride = gridDim.x * blockDim.x;
    for (; i < n4; i += stride) {
        float4 v = reinterpret_cast<const float4*>(in)[i];
        ushort4 o;
        o.x = f2bf(v.x); o.y = f2bf(v.y); o.z = f2bf(v.z); o.w = f2bf(v.w);
        reinterpret_cast<ushort4*>(out)[i] = o;
    }
}

// ------- pre-pass 2: w f32 [K][N] -> sign(w) bf16 transposed [N][K] (LDS transpose) --
__global__ void cvt_w_kernel(const float* __restrict__ w, ushort_t* __restrict__ wsT) {
    __shared__ ushort_t tile[64][65];   // +1 pad vs bank conflicts on transposed read
    const int t  = threadIdx.x;
    const int k0 = blockIdx.y * 64;
    const int n0 = blockIdx.x * 64;
    // read 64x64 f32 tile, coalesced along N; binarize to bf16 +/-1 (0 -> 0)
    #pragma unroll
    for (int p = 0; p < 4; ++p) {
        int kk = p * 16 + (t >> 4);
        int nn = (t & 15) * 4;
        float4 v = *reinterpret_cast<const float4*>(&w[(size_t)(k0 + kk) * N_DIM + n0 + nn]);
        tile[kk][nn + 0] = v.x > 0.f ? 0x3F80 : (v.x < 0.f ? 0xBF80 : 0);
        tile[kk][nn + 1] = v.y > 0.f ? 0x3F80 : (v.y < 0.f ? 0xBF80 : 0);
        tile[kk][nn + 2] = v.z > 0.f ? 0x3F80 : (v.z < 0.f ? 0xBF80 : 0);
        tile[kk][nn + 3] = v.w > 0.f ? 0x3F80 : (v.w < 0.f ? 0xBF80 : 0);
    }
    __syncthreads();
    // write transposed, coalesced along K (16B per thread per pass)
    #pragma unroll
    for (int q = 0; q < 2; ++q) {
        int r = q * 32 + (t >> 3);   // local n
        int c = (t & 7) * 8;         // local k
        ushort8 o;
        #pragma unroll
        for (int j = 0; j < 8; ++j) o[j] = tile[c + j][r];
        *reinterpret_cast<ushort8*>(&wsT[(size_t)(n0 + r) * K_DIM + k0 + c]) = o;
    }
}

// ---------------- main GEMM: C = relu(A(bf16) * BT^T(bf16) + bias), f32 out ----------
// m97 structure: 128x128 tile, BK=32, 4 waves (2x2 of 64x64), mfma 16x16x32 bf16,
// width-16 global_load_lds staging, 2 barriers per K-step.
#define BM 128
#define BN 128
#define BK 32

#define GLD(gsrc, ldst) __builtin_amdgcn_global_load_lds( \
    (const __attribute__((address_space(1))) unsigned int*)(gsrc), \
    (__attribute__((address_space(3))) unsigned int*)(ldst), 16, 0, 0)

__global__ __launch_bounds__(256, 2) void gemm_kernel(
    const ushort_t* __restrict__ A,    // [M][K] bf16 bits
    const ushort_t* __restrict__ BT,   // [N][K] bf16 bits = sign(w)^T
    const float* __restrict__ bias,
    float* __restrict__ C)             // [M][N] f32
{
    __shared__ ushort_t As[BM][BK];    // 8 KB, row stride 64 B
    __shared__ ushort_t Bs[BN][BK];    // 8 KB

    const int tid  = threadIdx.x;
    const int wave = tid >> 6;
    const int lane = tid & 63;
    const int wr   = wave >> 1;        // 0..1 : wave row in 2x2
    const int wc   = wave & 1;         // 0..1 : wave col

    const int bm = blockIdx.y * BM;
    const int bn = blockIdx.x * BN;

    floatx4 acc[4][4] = {};            // 4x4 of 16x16 frags = 64x64 per wave

    // staging: thread t covers row t/4 (+64 on second load), k-chunk (t%4)*8 elems
    const ushort_t* aptr = A  + (size_t)(bm + (tid >> 2)) * K_DIM + (tid & 3) * 8;
    const ushort_t* bptr = BT + (size_t)(bn + (tid >> 2)) * K_DIM + (tid & 3) * 8;

    const int frow = lane & 15;
    const int fk   = (lane >> 4) * 8;

    for (int k0 = 0; k0 < K_DIM; k0 += BK) {
        // --- stage global -> LDS (wave-uniform LDS base + lane*16 implicit) ---
        GLD(aptr + k0,               &As[wave * 16][0]);
        GLD(aptr + (size_t)64 * K_DIM + k0, &As[64 + wave * 16][0]);
        GLD(bptr + k0,               &Bs[wave * 16][0]);
        GLD(bptr + (size_t)64 * K_DIM + k0, &Bs[64 + wave * 16][0]);
        __syncthreads();   // compiler drains vmcnt(0) before s_barrier

        // --- fragments: 8 consecutive k per lane (ds_read_b128) ---
        short8 af[4], bfr[4];
        #pragma unroll
        for (int m = 0; m < 4; ++m)
            af[m] = *reinterpret_cast<const short8*>(&As[wr * 64 + m * 16 + frow][fk]);
        #pragma unroll
        for (int n = 0; n < 4; ++n)
            bfr[n] = *reinterpret_cast<const short8*>(&Bs[wc * 64 + n * 16 + frow][fk]);

        #pragma unroll
        for (int m = 0; m < 4; ++m)
            #pragma unroll
            for (int n = 0; n < 4; ++n)
                acc[m][n] = __builtin_amdgcn_mfma_f32_16x16x32_bf16(
                    af[m], bfr[n], acc[m][n], 0, 0, 0);
        __syncthreads();   // protect LDS before next stage
    }

    // --- epilogue: bias + relu, f32 store ---
    // D layout (measured m89): col = lane&15, row = (lane>>4)*4 + reg
    #pragma unroll
    for (int m = 0; m < 4; ++m) {
        const int row = bm + wr * 64 + m * 16 + (lane >> 4) * 4;
        #pragma unroll
        for (int n = 0; n < 4; ++n) {
            const int col = bn + wc * 64 + n * 16 + (lane & 15);
            const float bv = bias[col];
            float* cp = C + (size_t)row * N_DIM + col;
            #pragma unroll
            for (int r = 0; r < 4; ++r) {
                float v = acc[m][n][r] + bv;
                cp[(size_t)r * N_DIM] = v > 0.f ? v : 0.f;
            }
        }
    }
}

// ---------------- fallback (only if ws_size too small): naive tiled fp32 -------------
__global__ void naive_kernel(const float* __restrict__ x, const float* __restrict__ w,
                             const float* __restrict__ b, float* __restrict__ out) {
    __shared__ float xs[16][16];
    __shared__ float ws[16][17];
    const int row = blockIdx.y * 16 + threadIdx.y;
    const int col = blockIdx.x * 16 + threadIdx.x;
    float acc = 0.f;
    for (int k0 = 0; k0 < K_DIM; k0 += 16) {
        xs[threadIdx.y][threadIdx.x] = x[(size_t)row * K_DIM + k0 + threadIdx.x];
        float wv = w[(size_t)(k0 + threadIdx.y) * N_DIM + col];
        ws[threadIdx.y][threadIdx.x] = wv > 0.f ? 1.f : (wv < 0.f ? -1.f : 0.f);
        __syncthreads();
        #pragma unroll
        for (int kk = 0; kk < 16; ++kk) acc += xs[threadIdx.y][kk] * ws[kk][threadIdx.x];
        __syncthreads();
    }
    float v = acc + b[col];
    out[(size_t)row * N_DIM + col] = v > 0.f ? v : 0.f;
}

extern "C" void kernel_launch(void* const* d_in, const int* in_sizes, int n_in,
                              void* d_out, int out_size, void* d_ws, size_t ws_size,
                              hipStream_t stream) {
    const float* x = (const float*)d_in[0];
    const float* w = (const float*)d_in[1];
    const float* b = (const float*)d_in[2];
    float* out = (float*)d_out;

    const size_t xb_bytes = (size_t)M_DIM * K_DIM * sizeof(ushort_t);  // 64 MiB
    const size_t wb_bytes = (size_t)K_DIM * N_DIM * sizeof(ushort_t);  // 32 MiB

    if (ws_size >= xb_bytes + wb_bytes) {
        ushort_t* xb  = (ushort_t*)d_ws;
        ushort_t* wsT = (ushort_t*)((char*)d_ws + xb_bytes);
        cvt_x_kernel<<<2048, 256, 0, stream>>>(x, xb, (M_DIM * K_DIM) / 4);
        cvt_w_kernel<<<dim3(N_DIM / 64, K_DIM / 64), 256, 0, stream>>>(w, wsT);
        gemm_kernel<<<dim3(N_DIM / BN, M_DIM / BM), 256, 0, stream>>>(xb, wsT, b, out);
    } else {
        naive_kernel<<<dim3(N_DIM / 16, M_DIM / 16), dim3(16, 16), 0, stream>>>(x, w, b, out);
    }
}

// Round 2
// 342.429 us; speedup vs baseline: 1.0357x; 1.0357x over previous
//
#include <hip/hip_runtime.h>
#include <hip/hip_bf16.h>
#include <stdint.h>

#define M_DIM 8192
#define N_DIM 4096
#define K_DIM 4096

typedef __attribute__((ext_vector_type(8))) short short8;
typedef __attribute__((ext_vector_type(4))) float floatx4;
typedef __attribute__((ext_vector_type(8))) unsigned short ushort8;
typedef unsigned short ushort_t;

__device__ inline ushort_t f2bf(float f) {
    __hip_bfloat16 h = __float2bfloat16(f);  // RNE
    return *reinterpret_cast<ushort_t*>(&h);
}

// ---------------- pre-pass 1: x f32 -> bf16 (vectorized, memory-bound) ---------------
__global__ void cvt_x_kernel(const float* __restrict__ in, ushort_t* __restrict__ out, int n4) {
    int i = blockIdx.x * blockDim.x + threadIdx.x;
    int stride = gridDim.x * blockDim.x;
    for (; i < n4; i += stride) {
        float4 v = reinterpret_cast<const float4*>(in)[i];
        ushort4 o;
        o.x = f2bf(v.x); o.y = f2bf(v.y); o.z = f2bf(v.z); o.w = f2bf(v.w);
        reinterpret_cast<ushort4*>(out)[i] = o;
    }
}

// ------- pre-pass 2: w f32 [K][N] -> sign(w) bf16 transposed [N][K] (LDS transpose) --
__global__ void cvt_w_kernel(const float* __restrict__ w, ushort_t* __restrict__ wsT) {
    __shared__ ushort_t tile[64][65];
    const int t  = threadIdx.x;
    const int k0 = blockIdx.y * 64;
    const int n0 = blockIdx.x * 64;
    #pragma unroll
    for (int p = 0; p < 4; ++p) {
        int kk = p * 16 + (t >> 4);
        int nn = (t & 15) * 4;
        float4 v = *reinterpret_cast<const float4*>(&w[(size_t)(k0 + kk) * N_DIM + n0 + nn]);
        tile[kk][nn + 0] = v.x > 0.f ? 0x3F80 : (v.x < 0.f ? 0xBF80 : 0);
        tile[kk][nn + 1] = v.y > 0.f ? 0x3F80 : (v.y < 0.f ? 0xBF80 : 0);
        tile[kk][nn + 2] = v.z > 0.f ? 0x3F80 : (v.z < 0.f ? 0xBF80 : 0);
        tile[kk][nn + 3] = v.w > 0.f ? 0x3F80 : (v.w < 0.f ? 0xBF80 : 0);
    }
    __syncthreads();
    #pragma unroll
    for (int q = 0; q < 2; ++q) {
        int r = q * 32 + (t >> 3);
        int c = (t & 7) * 8;
        ushort8 o;
        #pragma unroll
        for (int j = 0; j < 8; ++j) o[j] = tile[c + j][r];
        *reinterpret_cast<ushort8*>(&wsT[(size_t)(n0 + r) * K_DIM + k0 + c]) = o;
    }
}

// =====================================================================================
// 256x256 8-phase GEMM (T1+T2+T3+T4+T5): C = relu(A * BT^T + bias)
// 8 waves (2M x 4N), BK=64, 2 K-tiles per dbuf pair, 4 phases per K-tile.
// LDS 128 KiB: As[2][2][128][64] + Bs[2][2][128][64], st_16x32 swizzle
// (byte ^= ((byte>>9)&1)<<5) applied to pre-swizzled global source + ds_read addr.
// vmcnt(4) once per K-tile (2 half-tiles stay in flight across the barrier).
// =====================================================================================
#define BM 256
#define BN 256
#define BK 64
#define NT (K_DIM / BK)

#define GLD(gsrc, ldst) __builtin_amdgcn_global_load_lds( \
    (const __attribute__((address_space(1))) unsigned int*)(gsrc), \
    (__attribute__((address_space(3))) unsigned int*)(ldst), 16, 0, 0)

__global__ __launch_bounds__(512, 2) void gemm8p_kernel(
    const ushort_t* __restrict__ A,    // [M][K] bf16 bits
    const ushort_t* __restrict__ BT,   // [N][K] bf16 bits = sign(w)^T
    const float* __restrict__ bias,
    float* __restrict__ C)             // [M][N] f32
{
    __shared__ ushort_t As[2][2][128 * 64];   // [dbuf][half][row*64+k], 64 KiB
    __shared__ ushort_t Bs[2][2][128 * 64];   // 64 KiB

    const int tid  = threadIdx.x;
    const int wave = tid >> 6;
    const int lane = tid & 63;
    const int wm   = wave >> 2;        // 0..1 : wave M-half (rows wm*128..+127)
    const int wn   = wave & 3;         // 0..3 : wave N-slot (cols wn*64..+63)
    const int bh   = wn >> 1;          // which B LDS half this wave reads
    const int brow0 = (wn & 1) * 64;   // row base inside that half

    // XCD-bijective swizzle (nwg = 512, divisible by 8)
    const int bid  = blockIdx.x;
    const int sbid = (bid & 7) * 64 + (bid >> 3);
    const int tn   = sbid & 15;        // N_DIM/BN = 16
    const int tm   = sbid >> 4;        // M_DIM/BM = 32
    const int bm   = tm * BM;
    const int bn   = tn * BN;

    // staging source geometry: thread covers LDS-linear bytes o = tid*16 (+8192 for
    // sweep 1); fetch from swizzled natural offset so = o ^ ((o>>9)&1)<<5.
    const int so   = (tid * 16) ^ (((tid >> 5) & 1) << 5);
    const int srow = so >> 7;              // 0..63 (sweep 1 adds 64)
    const int scol = (so & 127) >> 1;      // bf16 element col
    const int w512 = wave * 512;           // wave's LDS dest elem offset per sweep

    // read-side lane byte offset within a [128][64] half (swizzle folded in:
    // bit9 of the full offset == bit2 of (lane&15) for every fragment we read)
    const int laneOff = (lane & 15) * 128 +
                        (((lane >> 4) * 16) ^ (((lane >> 2) & 1) << 5));

    floatx4 acc[8][4] = {};

#define STAGE_HALF(G, R0, KOFS, LDST) do { \
    const ushort_t* _g = (G) + (size_t)((R0) + srow) * K_DIM + (KOFS) + scol; \
    GLD(_g, (LDST) + w512); \
    GLD(_g + (size_t)64 * K_DIM, (LDST) + 4096 + w512); \
  } while (0)

    // ---- prologue: tile0 {B0,B1,A0,A1}, tile1 {B0,B1}; wait all but newest 2 halves
    STAGE_HALF(BT, bn,        0, Bs[0][0]);
    STAGE_HALF(BT, bn + 128,  0, Bs[0][1]);
    STAGE_HALF(A,  bm,        0, As[0][0]);
    STAGE_HALF(A,  bm + 128,  0, As[0][1]);
    STAGE_HALF(BT, bn,       BK, Bs[1][0]);
    STAGE_HALF(BT, bn + 128, BK, Bs[1][1]);
    asm volatile("s_waitcnt vmcnt(4)" ::: "memory");
    __builtin_amdgcn_s_barrier();

    short8 a[4][2];      // current m-half A frags [mf][ks]
    short8 b[2][2][2];   // B frags [nq][nf][ks], live across the whole tile

    for (int t = 0; t < NT; ++t) {
        const int buf = t & 1;
        const char* Ar = (const char*)As[buf][wm];
        const char* Br = (const char*)Bs[buf][bh];
        const int kA = (t + 1 < NT ? t + 1 : NT - 1) * BK;   // clamp: tail reloads are never read
        const int kB = (t + 2 < NT ? t + 2 : NT - 1) * BK;

        // ---- phase 1: quadrant (mq=0, nq=0); 12 ds_reads; stage (t+1).A0 ----
        #pragma unroll
        for (int mf = 0; mf < 4; ++mf)
            #pragma unroll
            for (int ks = 0; ks < 2; ++ks)
                a[mf][ks] = *(const short8*)(Ar + laneOff + (mf * 16) * 128 + ks * 64);
        #pragma unroll
        for (int nf = 0; nf < 2; ++nf)
            #pragma unroll
            for (int ks = 0; ks < 2; ++ks)
                b[0][nf][ks] = *(const short8*)(Br + laneOff + (brow0 + nf * 16) * 128 + ks * 64);
        STAGE_HALF(A, bm, kA, As[buf ^ 1][0]);
        asm volatile("s_waitcnt lgkmcnt(8)" ::: "memory");
        __builtin_amdgcn_s_barrier();
        asm volatile("s_waitcnt lgkmcnt(0)" ::: "memory");
        __builtin_amdgcn_s_setprio(1);
        #pragma unroll
        for (int ks = 0; ks < 2; ++ks)
            #pragma unroll
            for (int mf = 0; mf < 4; ++mf)
                #pragma unroll
                for (int nf = 0; nf < 2; ++nf)
                    acc[mf][nf] = __builtin_amdgcn_mfma_f32_16x16x32_bf16(
                        a[mf][ks], b[0][nf][ks], acc[mf][nf], 0, 0, 0);
        __builtin_amdgcn_s_setprio(0);
        __builtin_amdgcn_s_barrier();

        // ---- phase 2: quadrant (mq=0, nq=1); 4 ds_reads; stage (t+1).A1 ----
        #pragma unroll
        for (int nf = 0; nf < 2; ++nf)
            #pragma unroll
            for (int ks = 0; ks < 2; ++ks)
                b[1][nf][ks] = *(const short8*)(Br + laneOff + (brow0 + 32 + nf * 16) * 128 + ks * 64);
        STAGE_HALF(A, bm + 128, kA, As[buf ^ 1][1]);
        __builtin_amdgcn_s_barrier();
        asm volatile("s_waitcnt lgkmcnt(0)" ::: "memory");
        __builtin_amdgcn_s_setprio(1);
        #pragma unroll
        for (int ks = 0; ks < 2; ++ks)
            #pragma unroll
            for (int mf = 0; mf < 4; ++mf)
                #pragma unroll
                for (int nf = 0; nf < 2; ++nf)
                    acc[mf][2 + nf] = __builtin_amdgcn_mfma_f32_16x16x32_bf16(
                        a[mf][ks], b[1][nf][ks], acc[mf][2 + nf], 0, 0, 0);
        __builtin_amdgcn_s_setprio(0);
        __builtin_amdgcn_s_barrier();

        // ---- phase 3: quadrant (mq=1, nq=0); 8 ds_reads; stage (t+2).B0 ----
        // (B reads of this buffer finished at phase 2's lgkmcnt(0)+barrier)
        #pragma unroll
        for (int mf = 0; mf < 4; ++mf)
            #pragma unroll
            for (int ks = 0; ks < 2; ++ks)
                a[mf][ks] = *(const short8*)(Ar + laneOff + ((64 + mf * 16)) * 128 + ks * 64);
        STAGE_HALF(BT, bn, kB, Bs[buf][0]);
        __builtin_amdgcn_s_barrier();
        asm volatile("s_waitcnt lgkmcnt(0)" ::: "memory");
        __builtin_amdgcn_s_setprio(1);
        #pragma unroll
        for (int ks = 0; ks < 2; ++ks)
            #pragma unroll
            for (int mf = 0; mf < 4; ++mf)
                #pragma unroll
                for (int nf = 0; nf < 2; ++nf)
                    acc[4 + mf][nf] = __builtin_amdgcn_mfma_f32_16x16x32_bf16(
                        a[mf][ks], b[0][nf][ks], acc[4 + mf][nf], 0, 0, 0);
        __builtin_amdgcn_s_setprio(0);
        __builtin_amdgcn_s_barrier();

        // ---- phase 4: quadrant (mq=1, nq=1); 0 ds_reads; stage (t+2).B1; vmcnt ----
        STAGE_HALF(BT, bn + 128, kB, Bs[buf][1]);
        __builtin_amdgcn_s_barrier();
        __builtin_amdgcn_s_setprio(1);
        #pragma unroll
        for (int ks = 0; ks < 2; ++ks)
            #pragma unroll
            for (int mf = 0; mf < 4; ++mf)
                #pragma unroll
                for (int nf = 0; nf < 2; ++nf)
                    acc[4 + mf][2 + nf] = __builtin_amdgcn_mfma_f32_16x16x32_bf16(
                        a[mf][ks], b[1][nf][ks], acc[4 + mf][2 + nf], 0, 0, 0);
        __builtin_amdgcn_s_setprio(0);
        // tile t+1 fully staged once all but the newest 4 loads (t+2.B0,B1) land
        asm volatile("s_waitcnt vmcnt(4)" ::: "memory");
        __builtin_amdgcn_s_barrier();
    }

    // ---- epilogue: bias + relu, f32 store ----
    float bv[4];
    #pragma unroll
    for (int nf = 0; nf < 4; ++nf)
        bv[nf] = bias[bn + wn * 64 + nf * 16 + (lane & 15)];
    #pragma unroll
    for (int mf = 0; mf < 8; ++mf) {
        const int row = bm + wm * 128 + mf * 16 + (lane >> 4) * 4;
        #pragma unroll
        for (int nf = 0; nf < 4; ++nf) {
            const int col = bn + wn * 64 + nf * 16 + (lane & 15);
            float* cp = C + (size_t)row * N_DIM + col;
            #pragma unroll
            for (int r = 0; r < 4; ++r) {
                float v = acc[mf][nf][r] + bv[nf];
                cp[(size_t)r * N_DIM] = v > 0.f ? v : 0.f;
            }
        }
    }
}

// ---------------- fallback (only if ws_size too small): naive tiled fp32 -------------
__global__ void naive_kernel(const float* __restrict__ x, const float* __restrict__ w,
                             const float* __restrict__ b, float* __restrict__ out) {
    __shared__ float xs[16][16];
    __shared__ float ws[16][17];
    const int row = blockIdx.y * 16 + threadIdx.y;
    const int col = blockIdx.x * 16 + threadIdx.x;
    float acc = 0.f;
    for (int k0 = 0; k0 < K_DIM; k0 += 16) {
        xs[threadIdx.y][threadIdx.x] = x[(size_t)row * K_DIM + k0 + threadIdx.x];
        float wv = w[(size_t)(k0 + threadIdx.y) * N_DIM + col];
        ws[threadIdx.y][threadIdx.x] = wv > 0.f ? 1.f : (wv < 0.f ? -1.f : 0.f);
        __syncthreads();
        #pragma unroll
        for (int kk = 0; kk < 16; ++kk) acc += xs[threadIdx.y][kk] * ws[kk][threadIdx.x];
        __syncthreads();
    }
    float v = acc + b[col];
    out[(size_t)row * N_DIM + col] = v > 0.f ? v : 0.f;
}

extern "C" void kernel_launch(void* const* d_in, const int* in_sizes, int n_in,
                              void* d_out, int out_size, void* d_ws, size_t ws_size,
                              hipStream_t stream) {
    const float* x = (const float*)d_in[0];
    const float* w = (const float*)d_in[1];
    const float* b = (const float*)d_in[2];
    float* out = (float*)d_out;

    const size_t xb_bytes = (size_t)M_DIM * K_DIM * sizeof(ushort_t);  // 64 MiB
    const size_t wb_bytes = (size_t)K_DIM * N_DIM * sizeof(ushort_t);  // 32 MiB

    if (ws_size >= xb_bytes + wb_bytes) {
        ushort_t* xb  = (ushort_t*)d_ws;
        ushort_t* wsT = (ushort_t*)((char*)d_ws + xb_bytes);
        cvt_x_kernel<<<2048, 256, 0, stream>>>(x, xb, (M_DIM * K_DIM) / 4);
        cvt_w_kernel<<<dim3(N_DIM / 64, K_DIM / 64), 256, 0, stream>>>(w, wsT);
        gemm8p_kernel<<<(M_DIM / BM) * (N_DIM / BN), 512, 0, stream>>>(xb, wsT, b, out);
    } else {
        naive_kernel<<<dim3(N_DIM / 16, M_DIM / 16), dim3(16, 16), 0, stream>>>(x, w, b, out);
    }
}

// Round 3
// 325.213 us; speedup vs baseline: 1.0905x; 1.0529x over previous
//
#include <hip/hip_runtime.h>
#include <hip/hip_bf16.h>
#include <stdint.h>

#define M_DIM 8192
#define N_DIM 4096
#define K_DIM 4096

typedef __attribute__((ext_vector_type(8))) short short8;
typedef __attribute__((ext_vector_type(4))) float floatx4;
typedef __attribute__((ext_vector_type(8))) unsigned short ushort8;
typedef unsigned short ushort_t;

__device__ inline ushort_t f2bf(float f) {
    __hip_bfloat16 h = __float2bfloat16(f);  // RNE
    return *reinterpret_cast<ushort_t*>(&h);
}

// ---------------- pre-pass 1: x f32 -> bf16 (vectorized, memory-bound) ---------------
__global__ void cvt_x_kernel(const float* __restrict__ in, ushort_t* __restrict__ out, int n4) {
    int i = blockIdx.x * blockDim.x + threadIdx.x;
    int stride = gridDim.x * blockDim.x;
    for (; i < n4; i += stride) {
        float4 v = reinterpret_cast<const float4*>(in)[i];
        ushort4 o;
        o.x = f2bf(v.x); o.y = f2bf(v.y); o.z = f2bf(v.z); o.w = f2bf(v.w);
        reinterpret_cast<ushort4*>(out)[i] = o;
    }
}

// ------- pre-pass 2: w f32 [K][N] -> sign(w) bf16 transposed [N][K] (LDS transpose) --
__global__ void cvt_w_kernel(const float* __restrict__ w, ushort_t* __restrict__ wsT) {
    __shared__ ushort_t tile[64][65];
    const int t  = threadIdx.x;
    const int k0 = blockIdx.y * 64;
    const int n0 = blockIdx.x * 64;
    #pragma unroll
    for (int p = 0; p < 4; ++p) {
        int kk = p * 16 + (t >> 4);
        int nn = (t & 15) * 4;
        float4 v = *reinterpret_cast<const float4*>(&w[(size_t)(k0 + kk) * N_DIM + n0 + nn]);
        tile[kk][nn + 0] = v.x > 0.f ? 0x3F80 : (v.x < 0.f ? 0xBF80 : 0);
        tile[kk][nn + 1] = v.y > 0.f ? 0x3F80 : (v.y < 0.f ? 0xBF80 : 0);
        tile[kk][nn + 2] = v.z > 0.f ? 0x3F80 : (v.z < 0.f ? 0xBF80 : 0);
        tile[kk][nn + 3] = v.w > 0.f ? 0x3F80 : (v.w < 0.f ? 0xBF80 : 0);
    }
    __syncthreads();
    #pragma unroll
    for (int q = 0; q < 2; ++q) {
        int r = q * 32 + (t >> 3);
        int c = (t & 7) * 8;
        ushort8 o;
        #pragma unroll
        for (int j = 0; j < 8; ++j) o[j] = tile[c + j][r];
        *reinterpret_cast<ushort8*>(&wsT[(size_t)(n0 + r) * K_DIM + k0 + c]) = o;
    }
}

// =====================================================================================
// 256x256 8-phase GEMM: C = relu(A * BT^T + bias)
// LDS halves are [128 rows][64 k] bf16 (128B rows). Swizzle (derived for this stride):
//   stored(row, c) = natural(row, c ^ f(row)),  f(row) = ((row>>1)&7)<<4  (col bits 4-6)
// -> every ds_read_b128 spreads 64 lanes evenly over all 32 banks (8 dwords/bank = floor).
// Write side: linear global_load_lds dest o = tid*16, source pre-swizzled
//   so = o ^ (((o>>8)&7)<<4)   (bits 8-10 of o are row bits 1-3).
// vmcnt(4) once per K-tile; raw s_barrier; setprio(1) around MFMA clusters.
// =====================================================================================
#define BM 256
#define BN 256
#define BK 64
#define NT (K_DIM / BK)

#define GLD(gsrc, ldst) __builtin_amdgcn_global_load_lds( \
    (const __attribute__((address_space(1))) unsigned int*)(gsrc), \
    (__attribute__((address_space(3))) unsigned int*)(ldst), 16, 0, 0)

__global__ __launch_bounds__(512, 2) void gemm8p_kernel(
    const ushort_t* __restrict__ A,    // [M][K] bf16 bits
    const ushort_t* __restrict__ BT,   // [N][K] bf16 bits = sign(w)^T
    const float* __restrict__ bias,
    float* __restrict__ C)             // [M][N] f32
{
    __shared__ ushort_t As[2][2][128 * 64];   // [dbuf][half][row*64+k], 64 KiB
    __shared__ ushort_t Bs[2][2][128 * 64];   // 64 KiB

    const int tid  = threadIdx.x;
    const int wave = tid >> 6;
    const int lane = tid & 63;
    const int wm   = wave >> 2;        // 0..1 : wave M-half (rows wm*128..+127)
    const int wn   = wave & 3;         // 0..3 : wave N-slot (cols wn*64..+63)
    const int bh   = wn >> 1;          // which B LDS half this wave reads
    const int brow0 = (wn & 1) * 64;   // row base inside that half

    // XCD-bijective swizzle (nwg = 512, divisible by 8)
    const int bid  = blockIdx.x;
    const int sbid = (bid & 7) * 64 + (bid >> 3);
    const int tn   = sbid & 15;        // N_DIM/BN = 16
    const int tm   = sbid >> 4;        // M_DIM/BM = 32
    const int bm   = tm * BM;
    const int bn   = tn * BN;

    // ---- staging source geometry (write side of the swizzle) ----
    const int so   = (tid * 16) ^ (((tid >> 4) & 7) << 4);  // o ^ (((o>>8)&7)<<4)
    const int srow = so >> 7;              // 0..63 (sweep 1 adds 64; row bits 1-3 unchanged)
    const int scol = (so & 127) >> 1;      // bf16 element col
    const int w512 = wave * 512;           // wave's LDS dest elem offset per sweep

    // ---- read side: ks folded INSIDE the XOR (carry-free, bits 4-6 only) ----
    const int laneRow = (lane & 15) * 128;
    const int fsw  = ((lane >> 1) & 7) << 4;           // f(row), row bits 1-3 = lane bits 1-3
    const int colX0 = (((lane >> 4) * 16) + 0)  ^ fsw;
    const int colX1 = (((lane >> 4) * 16) + 64) ^ fsw;

    floatx4 acc[8][4] = {};

#define STAGE_HALF(G, R0, KOFS, LDST) do { \
    const ushort_t* _g = (G) + (size_t)((R0) + srow) * K_DIM + (KOFS) + scol; \
    GLD(_g, (LDST) + w512); \
    GLD(_g + (size_t)64 * K_DIM, (LDST) + 4096 + w512); \
  } while (0)

    // ---- prologue: tile0 {B0,B1,A0,A1}, tile1 {B0,B1}; wait all but newest 2 halves
    STAGE_HALF(BT, bn,        0, Bs[0][0]);
    STAGE_HALF(BT, bn + 128,  0, Bs[0][1]);
    STAGE_HALF(A,  bm,        0, As[0][0]);
    STAGE_HALF(A,  bm + 128,  0, As[0][1]);
    STAGE_HALF(BT, bn,       BK, Bs[1][0]);
    STAGE_HALF(BT, bn + 128, BK, Bs[1][1]);
    asm volatile("s_waitcnt vmcnt(4)" ::: "memory");
    __builtin_amdgcn_s_barrier();

    short8 a[4][2];      // current m-half A frags [mf][ks]
    short8 b[2][2][2];   // B frags [nq][nf][ks], live across the whole tile

    for (int t = 0; t < NT; ++t) {
        const int buf = t & 1;
        const char* Ar = (const char*)As[buf][wm];
        const char* Br = (const char*)Bs[buf][bh];
        const int kA = (t + 1 < NT ? t + 1 : NT - 1) * BK;   // clamp: tail reloads never read
        const int kB = (t + 2 < NT ? t + 2 : NT - 1) * BK;

        // ---- phase 1: quadrant (mq=0, nq=0); 12 ds_reads; stage (t+1).A0 ----
        a[0][0] = *(const short8*)(Ar + laneRow + (0*16)*128 + colX0);
        a[0][1] = *(const short8*)(Ar + laneRow + (0*16)*128 + colX1);
        a[1][0] = *(const short8*)(Ar + laneRow + (1*16)*128 + colX0);
        a[1][1] = *(const short8*)(Ar + laneRow + (1*16)*128 + colX1);
        a[2][0] = *(const short8*)(Ar + laneRow + (2*16)*128 + colX0);
        a[2][1] = *(const short8*)(Ar + laneRow + (2*16)*128 + colX1);
        a[3][0] = *(const short8*)(Ar + laneRow + (3*16)*128 + colX0);
        a[3][1] = *(const short8*)(Ar + laneRow + (3*16)*128 + colX1);
        b[0][0][0] = *(const short8*)(Br + laneRow + (brow0 + 0*16)*128 + colX0);
        b[0][0][1] = *(const short8*)(Br + laneRow + (brow0 + 0*16)*128 + colX1);
        b[0][1][0] = *(const short8*)(Br + laneRow + (brow0 + 1*16)*128 + colX0);
        b[0][1][1] = *(const short8*)(Br + laneRow + (brow0 + 1*16)*128 + colX1);
        STAGE_HALF(A, bm, kA, As[buf ^ 1][0]);
        asm volatile("s_waitcnt lgkmcnt(8)" ::: "memory");
        __builtin_amdgcn_s_barrier();
        asm volatile("s_waitcnt lgkmcnt(0)" ::: "memory");
        __builtin_amdgcn_s_setprio(1);
        #pragma unroll
        for (int ks = 0; ks < 2; ++ks)
            #pragma unroll
            for (int mf = 0; mf < 4; ++mf)
                #pragma unroll
                for (int nf = 0; nf < 2; ++nf)
                    acc[mf][nf] = __builtin_amdgcn_mfma_f32_16x16x32_bf16(
                        a[mf][ks], b[0][nf][ks], acc[mf][nf], 0, 0, 0);
        __builtin_amdgcn_s_setprio(0);
        __builtin_amdgcn_s_barrier();

        // ---- phase 2: quadrant (mq=0, nq=1); 4 ds_reads; stage (t+1).A1 ----
        b[1][0][0] = *(const short8*)(Br + laneRow + (brow0 + 32 + 0*16)*128 + colX0);
        b[1][0][1] = *(const short8*)(Br + laneRow + (brow0 + 32 + 0*16)*128 + colX1);
        b[1][1][0] = *(const short8*)(Br + laneRow + (brow0 + 32 + 1*16)*128 + colX0);
        b[1][1][1] = *(const short8*)(Br + laneRow + (brow0 + 32 + 1*16)*128 + colX1);
        STAGE_HALF(A, bm + 128, kA, As[buf ^ 1][1]);
        __builtin_amdgcn_s_barrier();
        asm volatile("s_waitcnt lgkmcnt(0)" ::: "memory");
        __builtin_amdgcn_s_setprio(1);
        #pragma unroll
        for (int ks = 0; ks < 2; ++ks)
            #pragma unroll
            for (int mf = 0; mf < 4; ++mf)
                #pragma unroll
                for (int nf = 0; nf < 2; ++nf)
                    acc[mf][2 + nf] = __builtin_amdgcn_mfma_f32_16x16x32_bf16(
                        a[mf][ks], b[1][nf][ks], acc[mf][2 + nf], 0, 0, 0);
        __builtin_amdgcn_s_setprio(0);
        __builtin_amdgcn_s_barrier();

        // ---- phase 3: quadrant (mq=1, nq=0); 8 ds_reads; stage (t+2).B0 ----
        // (B reads of this buffer finished at phase 2's lgkmcnt(0)+barrier)
        a[0][0] = *(const short8*)(Ar + laneRow + ((64 + 0*16))*128 + colX0);
        a[0][1] = *(const short8*)(Ar + laneRow + ((64 + 0*16))*128 + colX1);
        a[1][0] = *(const short8*)(Ar + laneRow + ((64 + 1*16))*128 + colX0);
        a[1][1] = *(const short8*)(Ar + laneRow + ((64 + 1*16))*128 + colX1);
        a[2][0] = *(const short8*)(Ar + laneRow + ((64 + 2*16))*128 + colX0);
        a[2][1] = *(const short8*)(Ar + laneRow + ((64 + 2*16))*128 + colX1);
        a[3][0] = *(const short8*)(Ar + laneRow + ((64 + 3*16))*128 + colX0);
        a[3][1] = *(const short8*)(Ar + laneRow + ((64 + 3*16))*128 + colX1);
        STAGE_HALF(BT, bn, kB, Bs[buf][0]);
        __builtin_amdgcn_s_barrier();
        asm volatile("s_waitcnt lgkmcnt(0)" ::: "memory");
        __builtin_amdgcn_s_setprio(1);
        #pragma unroll
        for (int ks = 0; ks < 2; ++ks)
            #pragma unroll
            for (int mf = 0; mf < 4; ++mf)
                #pragma unroll
                for (int nf = 0; nf < 2; ++nf)
                    acc[4 + mf][nf] = __builtin_amdgcn_mfma_f32_16x16x32_bf16(
                        a[mf][ks], b[0][nf][ks], acc[4 + mf][nf], 0, 0, 0);
        __builtin_amdgcn_s_setprio(0);
        __builtin_amdgcn_s_barrier();

        // ---- phase 4: quadrant (mq=1, nq=1); 0 ds_reads; stage (t+2).B1; vmcnt ----
        STAGE_HALF(BT, bn + 128, kB, Bs[buf][1]);
        __builtin_amdgcn_s_barrier();
        __builtin_amdgcn_s_setprio(1);
        #pragma unroll
        for (int ks = 0; ks < 2; ++ks)
            #pragma unroll
            for (int mf = 0; mf < 4; ++mf)
                #pragma unroll
                for (int nf = 0; nf < 2; ++nf)
                    acc[4 + mf][2 + nf] = __builtin_amdgcn_mfma_f32_16x16x32_bf16(
                        a[mf][ks], b[1][nf][ks], acc[4 + mf][2 + nf], 0, 0, 0);
        __builtin_amdgcn_s_setprio(0);
        // tile t+1 fully staged once all but the newest 4 loads (t+2.B0,B1) land
        asm volatile("s_waitcnt vmcnt(4)" ::: "memory");
        __builtin_amdgcn_s_barrier();
    }

    // ---- epilogue: bias + relu, f32 store ----
    float bv[4];
    #pragma unroll
    for (int nf = 0; nf < 4; ++nf)
        bv[nf] = bias[bn + wn * 64 + nf * 16 + (lane & 15)];
    #pragma unroll
    for (int mf = 0; mf < 8; ++mf) {
        const int row = bm + wm * 128 + mf * 16 + (lane >> 4) * 4;
        #pragma unroll
        for (int nf = 0; nf < 4; ++nf) {
            const int col = bn + wn * 64 + nf * 16 + (lane & 15);
            float* cp = C + (size_t)row * N_DIM + col;
            #pragma unroll
            for (int r = 0; r < 4; ++r) {
                float v = acc[mf][nf][r] + bv[nf];
                cp[(size_t)r * N_DIM] = v > 0.f ? v : 0.f;
            }
        }
    }
}

// ---------------- fallback (only if ws_size too small): naive tiled fp32 -------------
__global__ void naive_kernel(const float* __restrict__ x, const float* __restrict__ w,
                             const float* __restrict__ b, float* __restrict__ out) {
    __shared__ float xs[16][16];
    __shared__ float ws[16][17];
    const int row = blockIdx.y * 16 + threadIdx.y;
    const int col = blockIdx.x * 16 + threadIdx.x;
    float acc = 0.f;
    for (int k0 = 0; k0 < K_DIM; k0 += 16) {
        xs[threadIdx.y][threadIdx.x] = x[(size_t)row * K_DIM + k0 + threadIdx.x];
        float wv = w[(size_t)(k0 + threadIdx.y) * N_DIM + col];
        ws[threadIdx.y][threadIdx.x] = wv > 0.f ? 1.f : (wv < 0.f ? -1.f : 0.f);
        __syncthreads();
        #pragma unroll
        for (int kk = 0; kk < 16; ++kk) acc += xs[threadIdx.y][kk] * ws[kk][threadIdx.x];
        __syncthreads();
    }
    float v = acc + b[col];
    out[(size_t)row * N_DIM + col] = v > 0.f ? v : 0.f;
}

extern "C" void kernel_launch(void* const* d_in, const int* in_sizes, int n_in,
                              void* d_out, int out_size, void* d_ws, size_t ws_size,
                              hipStream_t stream) {
    const float* x = (const float*)d_in[0];
    const float* w = (const float*)d_in[1];
    const float* b = (const float*)d_in[2];
    float* out = (float*)d_out;

    const size_t xb_bytes = (size_t)M_DIM * K_DIM * sizeof(ushort_t);  // 64 MiB
    const size_t wb_bytes = (size_t)K_DIM * N_DIM * sizeof(ushort_t);  // 32 MiB

    if (ws_size >= xb_bytes + wb_bytes) {
        ushort_t* xb  = (ushort_t*)d_ws;
        ushort_t* wsT = (ushort_t*)((char*)d_ws + xb_bytes);
        cvt_x_kernel<<<2048, 256, 0, stream>>>(x, xb, (M_DIM * K_DIM) / 4);
        cvt_w_kernel<<<dim3(N_DIM / 64, K_DIM / 64), 256, 0, stream>>>(w, wsT);
        gemm8p_kernel<<<(M_DIM / BM) * (N_DIM / BN), 512, 0, stream>>>(xb, wsT, b, out);
    } else {
        naive_kernel<<<dim3(N_DIM / 16, M_DIM / 16), dim3(16, 16), 0, stream>>>(x, w, b, out);
    }
}

// Round 4
// 229.516 us; speedup vs baseline: 1.5452x; 1.4169x over previous
//
#include <hip/hip_runtime.h>
#include <hip/hip_bf16.h>
#include <stdint.h>

#define M_DIM 8192
#define N_DIM 4096
#define K_DIM 4096

typedef __attribute__((ext_vector_type(4))) int   int4v;
typedef __attribute__((ext_vector_type(4))) float floatx4;

// ---------------- pre-pass 1: per-row quantize x f32 -> i8, scale = rowmax/127 -------
__global__ __launch_bounds__(256) void quant_x_kernel(const float* __restrict__ x,
                                                      signed char* __restrict__ xq,
                                                      float* __restrict__ xs) {
    const int row = blockIdx.x;
    const int tid = threadIdx.x;
    const int wave = tid >> 6, lane = tid & 63;
    const float4* xr = (const float4*)(x + (size_t)row * K_DIM);

    float4 v[4];
    float m = 0.f;
    #pragma unroll
    for (int j = 0; j < 4; ++j) {
        v[j] = xr[j * 256 + tid];
        m = fmaxf(m, fmaxf(fmaxf(fabsf(v[j].x), fabsf(v[j].y)),
                           fmaxf(fabsf(v[j].z), fabsf(v[j].w))));
    }
    #pragma unroll
    for (int off = 32; off >= 1; off >>= 1) m = fmaxf(m, __shfl_down(m, off));
    __shared__ float wm[4];
    if (lane == 0) wm[wave] = m;
    __syncthreads();
    const float M = fmaxf(fmaxf(wm[0], wm[1]), fmaxf(wm[2], wm[3]));
    const float inv = M > 0.f ? 127.f / M : 0.f;
    if (tid == 0) xs[row] = M > 0.f ? M / 127.f : 0.f;

    char4* xo = (char4*)(xq + (size_t)row * K_DIM);
    #pragma unroll
    for (int j = 0; j < 4; ++j) {
        char4 q;
        q.x = (signed char)__float2int_rn(v[j].x * inv);
        q.y = (signed char)__float2int_rn(v[j].y * inv);
        q.z = (signed char)__float2int_rn(v[j].z * inv);
        q.w = (signed char)__float2int_rn(v[j].w * inv);
        xo[j * 256 + tid] = q;
    }
}

// ------- pre-pass 2: w f32 [K][N] -> sign(w) i8 transposed [N][K] (LDS transpose) ----
__global__ __launch_bounds__(256) void cvt_w_kernel(const float* __restrict__ w,
                                                    signed char* __restrict__ wT) {
    __shared__ signed char tile[64][68];   // pad breaks pow2 column-read stride
    const int t  = threadIdx.x;
    const int k0 = blockIdx.y * 64;
    const int n0 = blockIdx.x * 64;
    #pragma unroll
    for (int p = 0; p < 4; ++p) {
        int kk = p * 16 + (t >> 4);
        int nn = (t & 15) * 4;
        float4 v = *reinterpret_cast<const float4*>(&w[(size_t)(k0 + kk) * N_DIM + n0 + nn]);
        tile[kk][nn + 0] = v.x > 0.f ? 1 : (v.x < 0.f ? -1 : 0);
        tile[kk][nn + 1] = v.y > 0.f ? 1 : (v.y < 0.f ? -1 : 0);
        tile[kk][nn + 2] = v.z > 0.f ? 1 : (v.z < 0.f ? -1 : 0);
        tile[kk][nn + 3] = v.w > 0.f ? 1 : (v.w < 0.f ? -1 : 0);
    }
    __syncthreads();
    const int r = t >> 2;          // local n row
    const int c = (t & 3) * 16;    // local k byte
    int4v o;
    signed char* op = (signed char*)&o;
    #pragma unroll
    for (int j = 0; j < 16; ++j) op[j] = tile[c + j][r];
    *reinterpret_cast<int4v*>(&wT[(size_t)(n0 + r) * K_DIM + k0 + c]) = o;
}

// =====================================================================================
// 256x256 i8 GEMM, 4-phase/K-tile schedule (structure identical to round 3):
//   C = relu( xs[row] * (Xq * signW^T) + bias )
// LDS halves are [128 rows][64 k] i8 (64-B rows) -> naturally conflict-free:
//   frag read addr = row*64 + (lane>>4)*16 spreads exactly 8 dwords/bank. No swizzle.
// mfma_i32_16x16x64_i8: one b128 per fragment covers full BK=64.
// Staging: 1 global_load_lds(16B) per thread per half-tile; vmcnt(2) once per K-tile.
// =====================================================================================
#define BM 256
#define BN 256
#define BK 64
#define NT (K_DIM / BK)

#define GLD(gsrc, ldst) __builtin_amdgcn_global_load_lds( \
    (const __attribute__((address_space(1))) unsigned int*)(gsrc), \
    (__attribute__((address_space(3))) unsigned int*)(ldst), 16, 0, 0)

__global__ __launch_bounds__(512, 2) void gemm_i8_kernel(
    const signed char* __restrict__ A,   // [M][K] i8 (quantized x)
    const signed char* __restrict__ BT,  // [N][K] i8 = sign(w)^T
    const float* __restrict__ xsc,       // [M] row scales
    const float* __restrict__ bias,
    float* __restrict__ C)               // [M][N] f32
{
    __shared__ signed char As[2][2][128 * 64];   // 16 KiB per buf pair -> 32 KiB
    __shared__ signed char Bs[2][2][128 * 64];   // 32 KiB

    const int tid  = threadIdx.x;
    const int wave = tid >> 6;
    const int lane = tid & 63;
    const int wm   = wave >> 2;        // 0..1 : wave M-half
    const int wn   = wave & 3;         // 0..3 : wave N-slot
    const int bh   = wn >> 1;          // B LDS half this wave reads
    const int brow0 = (wn & 1) * 64;   // row base inside that half

    // XCD-bijective swizzle (nwg = 512, divisible by 8)
    const int bid  = blockIdx.x;
    const int sbid = (bid & 7) * 64 + (bid >> 3);
    const int tn   = sbid & 15;
    const int tm   = sbid >> 4;
    const int bm   = tm * BM;
    const int bn   = tn * BN;

    // staging: thread t -> LDS byte t*16 (linear); source row = t>>2, col = (t&3)*16
    const int srow = tid >> 2;
    const int scol = (tid & 3) * 16;

    // fragment read offsets
    const int laneRow = (lane & 15) * 64;
    const int laneK   = (lane >> 4) * 16;

    int4v acc[8][4] = {};

#define STAGE_HALF(G, R0, KOFS, LDST) do { \
    GLD((G) + (size_t)((R0) + srow) * K_DIM + (KOFS) + scol, (LDST) + wave * 1024); \
  } while (0)

    // ---- prologue: tile0 {B0,B1,A0,A1}, tile1 {B0,B1}; wait tile0 (newest 2 remain)
    STAGE_HALF(BT, bn,        0, Bs[0][0]);
    STAGE_HALF(BT, bn + 128,  0, Bs[0][1]);
    STAGE_HALF(A,  bm,        0, As[0][0]);
    STAGE_HALF(A,  bm + 128,  0, As[0][1]);
    STAGE_HALF(BT, bn,       BK, Bs[1][0]);
    STAGE_HALF(BT, bn + 128, BK, Bs[1][1]);
    asm volatile("s_waitcnt vmcnt(2)" ::: "memory");
    __builtin_amdgcn_s_barrier();

    int4v a[4];       // current m-half A frags
    int4v b[2][2];    // B frags [nq][nf], live across the whole tile

    for (int t = 0; t < NT; ++t) {
        const int buf = t & 1;
        const char* Ar = (const char*)As[buf][wm];
        const char* Br = (const char*)Bs[buf][bh];
        const int kA = (t + 1 < NT ? t + 1 : NT - 1) * BK;   // tail reloads never read
        const int kB = (t + 2 < NT ? t + 2 : NT - 1) * BK;

        // ---- phase 1: (mq=0, nq=0); 6 ds_reads; stage (t+1).A0 ----
        a[0] = *(const int4v*)(Ar + (0*16)*64 + laneRow + laneK);
        a[1] = *(const int4v*)(Ar + (1*16)*64 + laneRow + laneK);
        a[2] = *(const int4v*)(Ar + (2*16)*64 + laneRow + laneK);
        a[3] = *(const int4v*)(Ar + (3*16)*64 + laneRow + laneK);
        b[0][0] = *(const int4v*)(Br + (brow0 + 0*16)*64 + laneRow + laneK);
        b[0][1] = *(const int4v*)(Br + (brow0 + 1*16)*64 + laneRow + laneK);
        STAGE_HALF(A, bm, kA, As[buf ^ 1][0]);
        __builtin_amdgcn_s_barrier();
        asm volatile("s_waitcnt lgkmcnt(0)" ::: "memory");
        __builtin_amdgcn_sched_barrier(0);
        __builtin_amdgcn_s_setprio(1);
        #pragma unroll
        for (int mf = 0; mf < 4; ++mf)
            #pragma unroll
            for (int nf = 0; nf < 2; ++nf)
                acc[mf][nf] = __builtin_amdgcn_mfma_i32_16x16x64_i8(
                    a[mf], b[0][nf], acc[mf][nf], 0, 0, 0);
        __builtin_amdgcn_s_setprio(0);
        __builtin_amdgcn_s_barrier();

        // ---- phase 2: (mq=0, nq=1); 2 ds_reads; stage (t+1).A1 ----
        b[1][0] = *(const int4v*)(Br + (brow0 + 32 + 0*16)*64 + laneRow + laneK);
        b[1][1] = *(const int4v*)(Br + (brow0 + 32 + 1*16)*64 + laneRow + laneK);
        STAGE_HALF(A, bm + 128, kA, As[buf ^ 1][1]);
        __builtin_amdgcn_s_barrier();
        asm volatile("s_waitcnt lgkmcnt(0)" ::: "memory");
        __builtin_amdgcn_sched_barrier(0);
        __builtin_amdgcn_s_setprio(1);
        #pragma unroll
        for (int mf = 0; mf < 4; ++mf)
            #pragma unroll
            for (int nf = 0; nf < 2; ++nf)
                acc[mf][2 + nf] = __builtin_amdgcn_mfma_i32_16x16x64_i8(
                    a[mf], b[1][nf], acc[mf][2 + nf], 0, 0, 0);
        __builtin_amdgcn_s_setprio(0);
        __builtin_amdgcn_s_barrier();

        // ---- phase 3: (mq=1, nq=0); 4 ds_reads; stage (t+2).B0 ----
        // (all waves' B reads of this buffer completed at phase 2's lgkmcnt+barrier)
        a[0] = *(const int4v*)(Ar + ((64 + 0*16))*64 + laneRow + laneK);
        a[1] = *(const int4v*)(Ar + ((64 + 1*16))*64 + laneRow + laneK);
        a[2] = *(const int4v*)(Ar + ((64 + 2*16))*64 + laneRow + laneK);
        a[3] = *(const int4v*)(Ar + ((64 + 3*16))*64 + laneRow + laneK);
        STAGE_HALF(BT, bn, kB, Bs[buf][0]);
        __builtin_amdgcn_s_barrier();
        asm volatile("s_waitcnt lgkmcnt(0)" ::: "memory");
        __builtin_amdgcn_sched_barrier(0);
        __builtin_amdgcn_s_setprio(1);
        #pragma unroll
        for (int mf = 0; mf < 4; ++mf)
            #pragma unroll
            for (int nf = 0; nf < 2; ++nf)
                acc[4 + mf][nf] = __builtin_amdgcn_mfma_i32_16x16x64_i8(
                    a[mf], b[0][nf], acc[4 + mf][nf], 0, 0, 0);
        __builtin_amdgcn_s_setprio(0);
        __builtin_amdgcn_s_barrier();

        // ---- phase 4: (mq=1, nq=1); 0 ds_reads; stage (t+2).B1; counted vmcnt ----
        STAGE_HALF(BT, bn + 128, kB, Bs[buf][1]);
        __builtin_amdgcn_s_barrier();
        __builtin_amdgcn_s_setprio(1);
        #pragma unroll
        for (int mf = 0; mf < 4; ++mf)
            #pragma unroll
            for (int nf = 0; nf < 2; ++nf)
                acc[4 + mf][2 + nf] = __builtin_amdgcn_mfma_i32_16x16x64_i8(
                    a[mf], b[1][nf], acc[4 + mf][2 + nf], 0, 0, 0);
        __builtin_amdgcn_s_setprio(0);
        // drain (t+1).A0,A1; keep (t+2).B0,B1 in flight
        asm volatile("s_waitcnt vmcnt(2)" ::: "memory");
        __builtin_amdgcn_s_barrier();
    }

    // ---- epilogue: dequant (per-row scale) + bias + relu, f32 store ----
    float bv[4];
    #pragma unroll
    for (int nf = 0; nf < 4; ++nf)
        bv[nf] = bias[bn + wn * 64 + nf * 16 + (lane & 15)];
    #pragma unroll
    for (int mf = 0; mf < 8; ++mf) {
        const int row0 = bm + wm * 128 + mf * 16 + (lane >> 4) * 4;
        float sr[4];
        #pragma unroll
        for (int r = 0; r < 4; ++r) sr[r] = xsc[row0 + r];
        #pragma unroll
        for (int nf = 0; nf < 4; ++nf) {
            const int col = bn + wn * 64 + nf * 16 + (lane & 15);
            float* cp = C + (size_t)row0 * N_DIM + col;
            #pragma unroll
            for (int r = 0; r < 4; ++r) {
                float v = (float)acc[mf][nf][r] * sr[r] + bv[nf];
                cp[(size_t)r * N_DIM] = v > 0.f ? v : 0.f;
            }
        }
    }
}

// ---------------- fallback (only if ws_size too small): naive tiled fp32 -------------
__global__ void naive_kernel(const float* __restrict__ x, const float* __restrict__ w,
                             const float* __restrict__ b, float* __restrict__ out) {
    __shared__ float xs[16][16];
    __shared__ float ws[16][17];
    const int row = blockIdx.y * 16 + threadIdx.y;
    const int col = blockIdx.x * 16 + threadIdx.x;
    float acc = 0.f;
    for (int k0 = 0; k0 < K_DIM; k0 += 16) {
        xs[threadIdx.y][threadIdx.x] = x[(size_t)row * K_DIM + k0 + threadIdx.x];
        float wv = w[(size_t)(k0 + threadIdx.y) * N_DIM + col];
        ws[threadIdx.y][threadIdx.x] = wv > 0.f ? 1.f : (wv < 0.f ? -1.f : 0.f);
        __syncthreads();
        #pragma unroll
        for (int kk = 0; kk < 16; ++kk) acc += xs[threadIdx.y][kk] * ws[kk][threadIdx.x];
        __syncthreads();
    }
    float v = acc + b[col];
    out[(size_t)row * N_DIM + col] = v > 0.f ? v : 0.f;
}

extern "C" void kernel_launch(void* const* d_in, const int* in_sizes, int n_in,
                              void* d_out, int out_size, void* d_ws, size_t ws_size,
                              hipStream_t stream) {
    const float* x = (const float*)d_in[0];
    const float* w = (const float*)d_in[1];
    const float* b = (const float*)d_in[2];
    float* out = (float*)d_out;

    const size_t xq_bytes = (size_t)M_DIM * K_DIM;                 // 32 MiB i8
    const size_t wT_bytes = (size_t)K_DIM * N_DIM;                 // 16 MiB i8
    const size_t xs_bytes = (size_t)M_DIM * sizeof(float);         // 32 KiB

    if (ws_size >= xq_bytes + wT_bytes + xs_bytes) {
        signed char* xq = (signed char*)d_ws;
        signed char* wT = (signed char*)((char*)d_ws + xq_bytes);
        float*       xs = (float*)((char*)d_ws + xq_bytes + wT_bytes);
        quant_x_kernel<<<M_DIM, 256, 0, stream>>>(x, xq, xs);
        cvt_w_kernel<<<dim3(N_DIM / 64, K_DIM / 64), 256, 0, stream>>>(w, wT);
        gemm_i8_kernel<<<(M_DIM / BM) * (N_DIM / BN), 512, 0, stream>>>(xq, wT, xs, b, out);
    } else {
        naive_kernel<<<dim3(N_DIM / 16, M_DIM / 16), dim3(16, 16), 0, stream>>>(x, w, b, out);
    }
}

// Round 5
// 218.415 us; speedup vs baseline: 1.6238x; 1.0508x over previous
//
#include <hip/hip_runtime.h>
#include <hip/hip_bf16.h>
#include <stdint.h>

#define M_DIM 8192
#define N_DIM 4096
#define K_DIM 4096

typedef __attribute__((ext_vector_type(4))) int   int4v;
typedef __attribute__((ext_vector_type(4))) float floatx4;

// ---------------- pre-pass 1: per-row quantize x f32 -> i8, scale = rowmax/127 -------
__global__ __launch_bounds__(256) void quant_x_kernel(const float* __restrict__ x,
                                                      signed char* __restrict__ xq,
                                                      float* __restrict__ xs) {
    const int row = blockIdx.x;
    const int tid = threadIdx.x;
    const int wave = tid >> 6, lane = tid & 63;
    const float4* xr = (const float4*)(x + (size_t)row * K_DIM);

    float4 v[4];
    float m = 0.f;
    #pragma unroll
    for (int j = 0; j < 4; ++j) {
        v[j] = xr[j * 256 + tid];
        m = fmaxf(m, fmaxf(fmaxf(fabsf(v[j].x), fabsf(v[j].y)),
                           fmaxf(fabsf(v[j].z), fabsf(v[j].w))));
    }
    #pragma unroll
    for (int off = 32; off >= 1; off >>= 1) m = fmaxf(m, __shfl_down(m, off));
    __shared__ float wm[4];
    if (lane == 0) wm[wave] = m;
    __syncthreads();
    const float M = fmaxf(fmaxf(wm[0], wm[1]), fmaxf(wm[2], wm[3]));
    const float inv = M > 0.f ? 127.f / M : 0.f;
    if (tid == 0) xs[row] = M > 0.f ? M / 127.f : 0.f;

    char4* xo = (char4*)(xq + (size_t)row * K_DIM);
    #pragma unroll
    for (int j = 0; j < 4; ++j) {
        char4 q;
        q.x = (signed char)__float2int_rn(v[j].x * inv);
        q.y = (signed char)__float2int_rn(v[j].y * inv);
        q.z = (signed char)__float2int_rn(v[j].z * inv);
        q.w = (signed char)__float2int_rn(v[j].w * inv);
        xo[j * 256 + tid] = q;
    }
}

// ------- pre-pass 2: w f32 [K][N] -> sign(w) i8 transposed [N][K] (LDS transpose) ----
__global__ __launch_bounds__(256) void cvt_w_kernel(const float* __restrict__ w,
                                                    signed char* __restrict__ wT) {
    __shared__ signed char tile[64][68];   // pad breaks pow2 column-read stride
    const int t  = threadIdx.x;
    const int k0 = blockIdx.y * 64;
    const int n0 = blockIdx.x * 64;
    #pragma unroll
    for (int p = 0; p < 4; ++p) {
        int kk = p * 16 + (t >> 4);
        int nn = (t & 15) * 4;
        float4 v = *reinterpret_cast<const float4*>(&w[(size_t)(k0 + kk) * N_DIM + n0 + nn]);
        tile[kk][nn + 0] = v.x > 0.f ? 1 : (v.x < 0.f ? -1 : 0);
        tile[kk][nn + 1] = v.y > 0.f ? 1 : (v.y < 0.f ? -1 : 0);
        tile[kk][nn + 2] = v.z > 0.f ? 1 : (v.z < 0.f ? -1 : 0);
        tile[kk][nn + 3] = v.w > 0.f ? 1 : (v.w < 0.f ? -1 : 0);
    }
    __syncthreads();
    const int r = t >> 2;          // local n row
    const int c = (t & 3) * 16;    // local k byte
    int4v o;
    signed char* op = (signed char*)&o;
    #pragma unroll
    for (int j = 0; j < 16; ++j) op[j] = tile[c + j][r];
    *reinterpret_cast<int4v*>(&wT[(size_t)(n0 + r) * K_DIM + k0 + c]) = o;
}

// =====================================================================================
// 256x256 i8 GEMM, 2 phases per K-tile:  C = relu( xs[row] * (Xq * signW^T) + bias )
// LDS halves are [128 rows][64 k] i8 (64-B rows). Quarter-wave bank analysis shows the
// natural layout is a 4-way conflict (banks (lane&1)*16 + q*4 only). Swizzle:
//   stored(row, c) = natural(row, c ^ f(row)),  f(row) = ((row>>1)&3)<<4
// -> each 16-lane quarter-wave puts exactly 2 dwords/bank (the floor).
// Read col:  colX = (lane>>4)*16 ^ ((lane>>1)&3)<<4   (closed in bits 5:4)
// Write side: linear global_load_lds dest o=tid*16; source col = ((tid&3)^((tid>>3)&3))*16
// Phases: P1 = {read B(all 4) + A rows 0-63; stage (t+1).A; 16 MFMA}
//         P2 = {read A rows 64-127;          stage (t+2).B; 16 MFMA; vmcnt(2)}
// 4 barriers per K-tile (was 8). vmcnt(2) keeps only (t+2).B in flight.
// =====================================================================================
#define BM 256
#define BN 256
#define BK 64
#define NT (K_DIM / BK)

#define GLD(gsrc, ldst) __builtin_amdgcn_global_load_lds( \
    (const __attribute__((address_space(1))) unsigned int*)(gsrc), \
    (__attribute__((address_space(3))) unsigned int*)(ldst), 16, 0, 0)

__global__ __launch_bounds__(512, 2) void gemm_i8_kernel(
    const signed char* __restrict__ A,   // [M][K] i8 (quantized x)
    const signed char* __restrict__ BT,  // [N][K] i8 = sign(w)^T
    const float* __restrict__ xsc,       // [M] row scales
    const float* __restrict__ bias,
    float* __restrict__ C)               // [M][N] f32
{
    __shared__ signed char As[2][2][128 * 64];   // 32 KiB
    __shared__ signed char Bs[2][2][128 * 64];   // 32 KiB

    const int tid  = threadIdx.x;
    const int wave = tid >> 6;
    const int lane = tid & 63;
    const int wm   = wave >> 2;        // 0..1 : wave M-half
    const int wn   = wave & 3;         // 0..3 : wave N-slot
    const int bh   = wn >> 1;          // B LDS half this wave reads
    const int brow0 = (wn & 1) * 64;   // row base inside that half

    // XCD-bijective swizzle (nwg = 512, divisible by 8)
    const int bid  = blockIdx.x;
    const int sbid = (bid & 7) * 64 + (bid >> 3);
    const int tn   = sbid & 15;
    const int tm   = sbid >> 4;
    const int bm   = tm * BM;
    const int bn   = tn * BN;

    // staging (write side of swizzle): dest linear o = tid*16; row = tid>>2;
    // source col = ((tid&3) ^ ((tid>>3)&3)) * 16   [row bits 2:1 = tid bits 4:3]
    const int srow = tid >> 2;
    const int scol = ((tid & 3) ^ ((tid >> 3) & 3)) * 16;

    // fragment read offsets (read side of swizzle)
    const int laneRow = (lane & 15) * 64;
    const int colX = ((lane >> 4) * 16) ^ (((lane >> 1) & 3) << 4);

    int4v acc[8][4] = {};

#define STAGE_HALF(G, R0, KOFS, LDST) do { \
    GLD((G) + (size_t)((R0) + srow) * K_DIM + (KOFS) + scol, (LDST) + wave * 1024); \
  } while (0)

    // ---- prologue: tile0 {B0,B1,A0,A1}, tile1 {B0,B1}; drain tile0, keep (1).B ----
    STAGE_HALF(BT, bn,        0, Bs[0][0]);
    STAGE_HALF(BT, bn + 128,  0, Bs[0][1]);
    STAGE_HALF(A,  bm,        0, As[0][0]);
    STAGE_HALF(A,  bm + 128,  0, As[0][1]);
    STAGE_HALF(BT, bn,       BK, Bs[1][0]);
    STAGE_HALF(BT, bn + 128, BK, Bs[1][1]);
    asm volatile("s_waitcnt vmcnt(2)" ::: "memory");
    __builtin_amdgcn_s_barrier();

    int4v a[4];    // current m-quadrant A frags
    int4v b[4];    // all 4 B n-frags, live across the whole tile

    for (int t = 0; t < NT; ++t) {
        const int buf = t & 1;
        const char* Ar = (const char*)As[buf][wm];
        const char* Br = (const char*)Bs[buf][bh];
        const int kA = (t + 1 < NT ? t + 1 : NT - 1) * BK;   // tail reloads never read
        const int kB = (t + 2 < NT ? t + 2 : NT - 1) * BK;

        // ---- phase 1: m-rows 0-63 x all n; 8 ds_reads; stage (t+1).A0,A1 ----
        a[0] = *(const int4v*)(Ar + (0*16)*64 + laneRow + colX);
        a[1] = *(const int4v*)(Ar + (1*16)*64 + laneRow + colX);
        a[2] = *(const int4v*)(Ar + (2*16)*64 + laneRow + colX);
        a[3] = *(const int4v*)(Ar + (3*16)*64 + laneRow + colX);
        b[0] = *(const int4v*)(Br + (brow0 +  0)*64 + laneRow + colX);
        b[1] = *(const int4v*)(Br + (brow0 + 16)*64 + laneRow + colX);
        b[2] = *(const int4v*)(Br + (brow0 + 32)*64 + laneRow + colX);
        b[3] = *(const int4v*)(Br + (brow0 + 48)*64 + laneRow + colX);
        STAGE_HALF(A, bm,       kA, As[buf ^ 1][0]);
        STAGE_HALF(A, bm + 128, kA, As[buf ^ 1][1]);
        __builtin_amdgcn_s_barrier();
        asm volatile("s_waitcnt lgkmcnt(0)" ::: "memory");
        __builtin_amdgcn_sched_barrier(0);
        __builtin_amdgcn_s_setprio(1);
        #pragma unroll
        for (int mf = 0; mf < 4; ++mf)
            #pragma unroll
            for (int nf = 0; nf < 4; ++nf)
                acc[mf][nf] = __builtin_amdgcn_mfma_i32_16x16x64_i8(
                    a[mf], b[nf], acc[mf][nf], 0, 0, 0);
        __builtin_amdgcn_s_setprio(0);
        __builtin_amdgcn_s_barrier();

        // ---- phase 2: m-rows 64-127 x all n; 4 ds_reads; stage (t+2).B0,B1 ----
        // (all waves' B reads of Bs[buf] completed at phase 1's lgkmcnt+barrier)
        a[0] = *(const int4v*)(Ar + ((64 + 0*16))*64 + laneRow + colX);
        a[1] = *(const int4v*)(Ar + ((64 + 1*16))*64 + laneRow + colX);
        a[2] = *(const int4v*)(Ar + ((64 + 2*16))*64 + laneRow + colX);
        a[3] = *(const int4v*)(Ar + ((64 + 3*16))*64 + laneRow + colX);
        STAGE_HALF(BT, bn,       kB, Bs[buf][0]);
        STAGE_HALF(BT, bn + 128, kB, Bs[buf][1]);
        __builtin_amdgcn_s_barrier();
        asm volatile("s_waitcnt lgkmcnt(0)" ::: "memory");
        __builtin_amdgcn_sched_barrier(0);
        __builtin_amdgcn_s_setprio(1);
        #pragma unroll
        for (int mf = 0; mf < 4; ++mf)
            #pragma unroll
            for (int nf = 0; nf < 4; ++nf)
                acc[4 + mf][nf] = __builtin_amdgcn_mfma_i32_16x16x64_i8(
                    a[mf], b[nf], acc[4 + mf][nf], 0, 0, 0);
        __builtin_amdgcn_s_setprio(0);
        // drain (t+1).A0,A1; keep (t+2).B0,B1 in flight
        asm volatile("s_waitcnt vmcnt(2)" ::: "memory");
        __builtin_amdgcn_s_barrier();
    }

    // ---- epilogue: dequant (per-row scale) + bias + relu, f32 store ----
    float bv[4];
    #pragma unroll
    for (int nf = 0; nf < 4; ++nf)
        bv[nf] = bias[bn + wn * 64 + nf * 16 + (lane & 15)];
    #pragma unroll
    for (int mf = 0; mf < 8; ++mf) {
        const int row0 = bm + wm * 128 + mf * 16 + (lane >> 4) * 4;
        float sr[4];
        #pragma unroll
        for (int r = 0; r < 4; ++r) sr[r] = xsc[row0 + r];
        #pragma unroll
        for (int nf = 0; nf < 4; ++nf) {
            const int col = bn + wn * 64 + nf * 16 + (lane & 15);
            float* cp = C + (size_t)row0 * N_DIM + col;
            #pragma unroll
            for (int r = 0; r < 4; ++r) {
                float v = (float)acc[mf][nf][r] * sr[r] + bv[nf];
                cp[(size_t)r * N_DIM] = v > 0.f ? v : 0.f;
            }
        }
    }
}

// ---------------- fallback (only if ws_size too small): naive tiled fp32 -------------
__global__ void naive_kernel(const float* __restrict__ x, const float* __restrict__ w,
                             const float* __restrict__ b, float* __restrict__ out) {
    __shared__ float xs[16][16];
    __shared__ float ws[16][17];
    const int row = blockIdx.y * 16 + threadIdx.y;
    const int col = blockIdx.x * 16 + threadIdx.x;
    float acc = 0.f;
    for (int k0 = 0; k0 < K_DIM; k0 += 16) {
        xs[threadIdx.y][threadIdx.x] = x[(size_t)row * K_DIM + k0 + threadIdx.x];
        float wv = w[(size_t)(k0 + threadIdx.y) * N_DIM + col];
        ws[threadIdx.y][threadIdx.x] = wv > 0.f ? 1.f : (wv < 0.f ? -1.f : 0.f);
        __syncthreads();
        #pragma unroll
        for (int kk = 0; kk < 16; ++kk) acc += xs[threadIdx.y][kk] * ws[kk][threadIdx.x];
        __syncthreads();
    }
    float v = acc + b[col];
    out[(size_t)row * N_DIM + col] = v > 0.f ? v : 0.f;
}

extern "C" void kernel_launch(void* const* d_in, const int* in_sizes, int n_in,
                              void* d_out, int out_size, void* d_ws, size_t ws_size,
                              hipStream_t stream) {
    const float* x = (const float*)d_in[0];
    const float* w = (const float*)d_in[1];
    const float* b = (const float*)d_in[2];
    float* out = (float*)d_out;

    const size_t xq_bytes = (size_t)M_DIM * K_DIM;                 // 32 MiB i8
    const size_t wT_bytes = (size_t)K_DIM * N_DIM;                 // 16 MiB i8
    const size_t xs_bytes = (size_t)M_DIM * sizeof(float);         // 32 KiB

    if (ws_size >= xq_bytes + wT_bytes + xs_bytes) {
        signed char* xq = (signed char*)d_ws;
        signed char* wT = (signed char*)((char*)d_ws + xq_bytes);
        float*       xs = (float*)((char*)d_ws + xq_bytes + wT_bytes);
        quant_x_kernel<<<M_DIM, 256, 0, stream>>>(x, xq, xs);
        cvt_w_kernel<<<dim3(N_DIM / 64, K_DIM / 64), 256, 0, stream>>>(w, wT);
        gemm_i8_kernel<<<(M_DIM / BM) * (N_DIM / BN), 512, 0, stream>>>(xq, wT, xs, b, out);
    } else {
        naive_kernel<<<dim3(N_DIM / 16, M_DIM / 16), dim3(16, 16), 0, stream>>>(x, w, b, out);
    }
}